// Round 3
// baseline (66.098 us; speedup 1.0000x reference)
//
#include <hip/hip_runtime.h>

// One-way Chamfer (L1, K=1): out[0] = mean_i min_j ||x_i - y_j||_1 ; out[1..N] = 0
// N = M = 16384, D = 3, fp32.
//
// R3: back to LDS staging (R1) but with RB=8 x-points per thread so one
// broadcast ds_read_b128 (~12 cyc/CU, shared by 4 SIMDs) feeds ~176 SIMD-cycles
// of VALU -> VALU-bound (R1 with RB=2 was LDS-bus-bound; R2's scalar-path idea
// failed: compiler won't scalarize loads, SGPR_Count=32 proved it).
// Atomics replaced by partial-min stores + reduce pass (ws permitting).

#define TPB 256
#define RB 8
#define PTS_PER_BLOCK (TPB * RB)   // 2048
#define MSEG 256                   // y-points staged in LDS per block

template <bool ATOMIC>
__global__ __launch_bounds__(TPB) void chamfer_kernel(
    const float* __restrict__ pc1, const float* __restrict__ flow,
    const float* __restrict__ pc2, float* __restrict__ partial,
    unsigned* __restrict__ minbits, int N, int M) {
    __shared__ float4 ys[MSEG];

    const int t  = threadIdx.x;
    const int y0 = blockIdx.y * MSEG;
    const int len = (M - y0 < MSEG) ? (M - y0) : MSEG;

    // stage this block's pc2 segment into LDS as padded float4
    for (int j = t; j < len; j += TPB) {
        const int g = y0 + j;
        ys[j] = make_float4(pc2[3 * g], pc2[3 * g + 1], pc2[3 * g + 2], 0.0f);
    }

    // load + deform this thread's 8 x-points (stride TPB for coalescing)
    const int ibase = blockIdx.x * PTS_PER_BLOCK + t;
    float ax[RB], ay[RB], az[RB];
#pragma unroll
    for (int r = 0; r < RB; ++r) {
        const int i = ibase + r * TPB;
        const int ic = (i < N) ? i : (N - 1);
        ax[r] = pc1[3 * ic]     + flow[3 * ic];
        ay[r] = pc1[3 * ic + 1] + flow[3 * ic + 1];
        az[r] = pc1[3 * ic + 2] + flow[3 * ic + 2];
    }
    __syncthreads();

    float m[RB];
#pragma unroll
    for (int r = 0; r < RB; ++r) m[r] = 3.0e38f;

    int j = 0;
#pragma unroll 2
    for (; j + 2 <= len; j += 2) {
        const float4 A = ys[j];
        const float4 B = ys[j + 1];
#pragma unroll
        for (int r = 0; r < RB; ++r) {
            const float d0 = fabsf(ax[r] - A.x) + fabsf(ay[r] - A.y) + fabsf(az[r] - A.z);
            const float d1 = fabsf(ax[r] - B.x) + fabsf(ay[r] - B.y) + fabsf(az[r] - B.z);
            m[r] = fminf(fminf(m[r], d0), d1);   // -> v_min3_f32
        }
    }
    if (j < len) {
        const float4 A = ys[j];
#pragma unroll
        for (int r = 0; r < RB; ++r)
            m[r] = fminf(m[r], fabsf(ax[r] - A.x) + fabsf(ay[r] - A.y) + fabsf(az[r] - A.z));
    }

#pragma unroll
    for (int r = 0; r < RB; ++r) {
        const int i = ibase + r * TPB;
        if (i < N) {
            if (ATOMIC) {
                // exact, order-independent: uint order == float order for nonneg
                atomicMin(&minbits[i], __float_as_uint(m[r]));
            } else {
                partial[(size_t)blockIdx.y * N + i] = m[r];
            }
        }
    }
}

// per-point min over `rows` partials, then block partial sums
__global__ __launch_bounds__(256) void reduce_kernel(
    const float* __restrict__ partial, float* __restrict__ blocksums,
    int N, int rows) {
    const int i = blockIdx.x * 256 + threadIdx.x;
    float v = 3.0e38f;
    if (i < N) {
        for (int s = 0; s < rows; ++s)
            v = fminf(v, partial[(size_t)s * N + i]);
    } else {
        v = 0.0f;
    }
    float sv = (i < N) ? v : 0.0f;
#pragma unroll
    for (int off = 32; off > 0; off >>= 1) sv += __shfl_down(sv, off, 64);
    __shared__ float ls[4];
    const int wid = threadIdx.x >> 6, lane = threadIdx.x & 63;
    if (lane == 0) ls[wid] = sv;
    __syncthreads();
    if (threadIdx.x == 0) {
        float s = ls[0] + ls[1] + ls[2] + ls[3];
        blocksums[blockIdx.x] = s;
    }
}

__global__ void final_kernel(const float* __restrict__ blocksums, int nPart,
                             float* __restrict__ out, float invN) {
    float v = 0.0f;
    for (int i = threadIdx.x; i < nPart; i += 64) v += blocksums[i];
#pragma unroll
    for (int off = 32; off > 0; off >>= 1) v += __shfl_down(v, off, 64);
    if (threadIdx.x == 0) out[0] = v * invN;
}

extern "C" void kernel_launch(void* const* d_in, const int* in_sizes, int n_in,
                              void* d_out, int out_size, void* d_ws, size_t ws_size,
                              hipStream_t stream) {
    const float* pc1  = (const float*)d_in[0];
    const float* flow = (const float*)d_in[1];
    const float* pc2  = (const float*)d_in[2];
    float* out = (float*)d_out;

    const int N = in_sizes[0] / 3;
    const int M = in_sizes[2] / 3;

    const int nbN    = (N + PTS_PER_BLOCK - 1) / PTS_PER_BLOCK;  // 8
    const int msplit = (M + MSEG - 1) / MSEG;                    // 64
    const int nb2    = (N + 255) / 256;                          // 64

    // freespace_loss part of d_out stays zero; out[0] overwritten by final
    hipMemsetAsync(d_out, 0, (size_t)out_size * sizeof(float), stream);

    const size_t need = (size_t)msplit * (size_t)N * sizeof(float) + 4096;
    if (ws_size >= need) {
        // store path: no atomics
        float* partial   = (float*)d_ws;
        float* blocksums = (float*)((char*)d_ws + (size_t)msplit * N * sizeof(float));
        chamfer_kernel<false><<<dim3(nbN, msplit), TPB, 0, stream>>>(
            pc1, flow, pc2, partial, nullptr, N, M);
        reduce_kernel<<<nb2, 256, 0, stream>>>(partial, blocksums, N, msplit);
        final_kernel<<<1, 64, 0, stream>>>(blocksums, nb2, out, 1.0f / (float)N);
    } else {
        // atomic fallback
        unsigned* minbits  = (unsigned*)d_ws;
        float* blocksums   = (float*)((char*)d_ws + (size_t)N * sizeof(unsigned));
        // 0x7F7F7F7F = 3.39e38f sentinel; uint order == float order for nonneg
        hipMemsetAsync(minbits, 0x7F, (size_t)N * sizeof(unsigned), stream);
        chamfer_kernel<true><<<dim3(nbN, msplit), TPB, 0, stream>>>(
            pc1, flow, pc2, nullptr, minbits, N, M);
        reduce_kernel<<<nb2, 256, 0, stream>>>((const float*)minbits, blocksums, N, 1);
        final_kernel<<<1, 64, 0, stream>>>(blocksums, nb2, out, 1.0f / (float)N);
    }
}

// Round 4
// 49.972 us; speedup vs baseline: 1.3227x; 1.3227x over previous
//
#include <hip/hip_runtime.h>

// One-way Chamfer (L1, K=1): out[0] = mean_i min_j ||x_i - y_j||_1 ; out[1..N] = 0
// N = M = 16384, D = 3, fp32.
//
// R4: occupancy was the R3 killer (512 blocks -> 14.9% occupancy, VALU idle
// 33%). Grid now 1024 blocks (4/CU, 4 waves/SIMD). LDS y-tile stored SoA so
// 4 y-points cost 3 broadcast ds_read_b128 (LDS pipe ~41% of VALU timeline).
// Cross-block combine via uint atomicMin (order-independent, exact for
// nonneg floats); reduce = one 1024-thread block over 64 KB.

#define TPB 256
#define RB 8
#define PTS_PER_BLOCK (TPB * RB)   // 2048
#define MSEG 128                   // y-points staged in LDS per block

__global__ __launch_bounds__(TPB) void chamfer_kernel(
    const float* __restrict__ pc1, const float* __restrict__ flow,
    const float* __restrict__ pc2, unsigned* __restrict__ minbits,
    int N, int M) {
    __shared__ float ysx[MSEG], ysy[MSEG], ysz[MSEG];

    const int t  = threadIdx.x;
    const int y0 = blockIdx.y * MSEG;
    const int len = (M - y0 < MSEG) ? (M - y0) : MSEG;

    // stage this block's pc2 segment into LDS, SoA
    for (int j = t; j < len; j += TPB) {
        const int g = y0 + j;
        ysx[j] = pc2[3 * g];
        ysy[j] = pc2[3 * g + 1];
        ysz[j] = pc2[3 * g + 2];
    }

    // load + deform this thread's 8 x-points (stride TPB for coalescing)
    const int ibase = blockIdx.x * PTS_PER_BLOCK + t;
    float ax[RB], ay[RB], az[RB];
#pragma unroll
    for (int r = 0; r < RB; ++r) {
        const int i = ibase + r * TPB;
        const int ic = (i < N) ? i : (N - 1);
        ax[r] = pc1[3 * ic]     + flow[3 * ic];
        ay[r] = pc1[3 * ic + 1] + flow[3 * ic + 1];
        az[r] = pc1[3 * ic + 2] + flow[3 * ic + 2];
    }
    __syncthreads();

    float m[RB];
#pragma unroll
    for (int r = 0; r < RB; ++r) m[r] = 3.0e38f;

    if ((len & 3) == 0) {
        const float4* __restrict__ X4 = (const float4*)ysx;
        const float4* __restrict__ Y4 = (const float4*)ysy;
        const float4* __restrict__ Z4 = (const float4*)ysz;
#pragma unroll 2
        for (int q = 0; q < len / 4; ++q) {
            const float4 YX = X4[q];   // broadcast ds_read_b128, all lanes same addr
            const float4 YY = Y4[q];
            const float4 YZ = Z4[q];
#pragma unroll
            for (int r = 0; r < RB; ++r) {
                const float d0 = fabsf(ax[r] - YX.x) + fabsf(ay[r] - YY.x) + fabsf(az[r] - YZ.x);
                const float d1 = fabsf(ax[r] - YX.y) + fabsf(ay[r] - YY.y) + fabsf(az[r] - YZ.y);
                const float d2 = fabsf(ax[r] - YX.z) + fabsf(ay[r] - YY.z) + fabsf(az[r] - YZ.z);
                const float d3 = fabsf(ax[r] - YX.w) + fabsf(ay[r] - YY.w) + fabsf(az[r] - YZ.w);
                m[r] = fminf(fminf(m[r], d0), d1);   // -> v_min3_f32
                m[r] = fminf(fminf(m[r], d2), d3);   // -> v_min3_f32
            }
        }
    } else {
        for (int j = 0; j < len; ++j) {
            const float yx = ysx[j], yy = ysy[j], yz = ysz[j];
#pragma unroll
            for (int r = 0; r < RB; ++r)
                m[r] = fminf(m[r], fabsf(ax[r] - yx) + fabsf(ay[r] - yy) + fabsf(az[r] - yz));
        }
    }

    // exact, order-independent combine: uint order == float order for nonneg
#pragma unroll
    for (int r = 0; r < RB; ++r) {
        const int i = ibase + r * TPB;
        if (i < N) atomicMin(&minbits[i], __float_as_uint(m[r]));
    }
}

// single-block deterministic reduction: out[0] = sum(min) / N
__global__ __launch_bounds__(1024) void reduce_kernel(
    const unsigned* __restrict__ minbits, float* __restrict__ out, int N) {
    float s = 0.0f;
    const uint4* p = (const uint4*)minbits;
    for (int k = threadIdx.x; k < N / 4; k += 1024) {
        uint4 v = p[k];
        s += __uint_as_float(v.x) + __uint_as_float(v.y) +
             __uint_as_float(v.z) + __uint_as_float(v.w);
    }
    for (int k = (N / 4) * 4 + threadIdx.x; k < N; k += 1024)
        s += __uint_as_float(minbits[k]);
#pragma unroll
    for (int off = 32; off > 0; off >>= 1) s += __shfl_down(s, off, 64);
    __shared__ float ls[16];
    const int wid = threadIdx.x >> 6, lane = threadIdx.x & 63;
    if (lane == 0) ls[wid] = s;
    __syncthreads();
    if (threadIdx.x == 0) {
        float tot = 0.0f;
        for (int w = 0; w < 16; ++w) tot += ls[w];
        out[0] = tot / (float)N;
    }
}

extern "C" void kernel_launch(void* const* d_in, const int* in_sizes, int n_in,
                              void* d_out, int out_size, void* d_ws, size_t ws_size,
                              hipStream_t stream) {
    const float* pc1  = (const float*)d_in[0];
    const float* flow = (const float*)d_in[1];
    const float* pc2  = (const float*)d_in[2];
    float* out = (float*)d_out;

    const int N = in_sizes[0] / 3;
    const int M = in_sizes[2] / 3;

    unsigned* minbits = (unsigned*)d_ws;

    // freespace_loss part of d_out stays zero; out[0] overwritten by reduce
    hipMemsetAsync(d_out, 0, (size_t)out_size * sizeof(float), stream);
    // 0x7F7F7F7F = 3.39e38f sentinel; uint order == float order for nonneg
    hipMemsetAsync(minbits, 0x7F, (size_t)N * sizeof(unsigned), stream);

    const int nbN    = (N + PTS_PER_BLOCK - 1) / PTS_PER_BLOCK;  // 8
    const int msplit = (M + MSEG - 1) / MSEG;                    // 128 -> grid 1024

    chamfer_kernel<<<dim3(nbN, msplit), TPB, 0, stream>>>(pc1, flow, pc2, minbits, N, M);
    reduce_kernel<<<1, 1024, 0, stream>>>(minbits, out, N);
}

// Round 5
// 44.463 us; speedup vs baseline: 1.4866x; 1.1239x over previous
//
#include <hip/hip_runtime.h>

// One-way Chamfer (L1, K=1): out[0] = mean_i min_j ||x_i - y_j||_1 ; out[1..N] = 0
// N = M = 16384, D = 3, fp32.
//
// R5: R4 counters showed ~8.8 VALU instr/pair (VALUBusy*dur = 30us vs 18.8us
// ideal): compiler didn't fold fabs into add src-modifiers nor fuse fminf
// chains into v_min3_f32 (needs nnan proof). Fix: inline-asm 11-instr block
// per 2 (x,y) pairs = exactly 5.5 instr/pair. Also software-pipeline the LDS
// tile reads (prefetch q+1 into regs during q's compute) to hide ds_read
// latency. Structure otherwise = R4 (SoA LDS tile, RB=8, grid 8x128,
// uint atomicMin combine, single-block reduce).

#define TPB 256
#define RB 8
#define PTS_PER_BLOCK (TPB * RB)   // 2048
#define MSEG 128                   // y-points staged in LDS per block

// d0 = |AX-Y0X|+|AY-Y0Y|+|AZ-Y0Z|; d1 = |AX-Y1X|+...; MR = min3(MR, d0, d1)
// 11 VALU instrs for 2 pairs; abs folded as source modifiers; min3 exact for
// the finite nonneg values here.
#define DIST2(MR, AXv, AYv, AZv, Y0X, Y0Y, Y0Z, Y1X, Y1Y, Y1Z)            \
  {                                                                        \
    float t0, t1, t2, t3;                                                  \
    asm("v_sub_f32 %1, %5, %8\n\t"                                         \
        "v_sub_f32 %2, %6, %9\n\t"                                         \
        "v_sub_f32 %3, %7, %10\n\t"                                        \
        "v_sub_f32 %4, %5, %11\n\t"                                        \
        "v_add_f32 %1, |%1|, |%2|\n\t"                                     \
        "v_sub_f32 %2, %6, %12\n\t"                                        \
        "v_add_f32 %1, %1, |%3|\n\t"                                       \
        "v_sub_f32 %3, %7, %13\n\t"                                        \
        "v_add_f32 %4, |%4|, |%2|\n\t"                                     \
        "v_add_f32 %4, %4, |%3|\n\t"                                       \
        "v_min3_f32 %0, %0, %1, %4"                                        \
        : "+v"(MR), "=&v"(t0), "=&v"(t1), "=&v"(t2), "=&v"(t3)             \
        : "v"(AXv), "v"(AYv), "v"(AZv),                                    \
          "v"(Y0X), "v"(Y0Y), "v"(Y0Z), "v"(Y1X), "v"(Y1Y), "v"(Y1Z));    \
  }

__global__ __launch_bounds__(TPB) void chamfer_kernel(
    const float* __restrict__ pc1, const float* __restrict__ flow,
    const float* __restrict__ pc2, unsigned* __restrict__ minbits,
    int N, int M) {
    __shared__ float ysx[MSEG], ysy[MSEG], ysz[MSEG];

    const int t  = threadIdx.x;
    const int y0 = blockIdx.y * MSEG;
    const int len = (M - y0 < MSEG) ? (M - y0) : MSEG;

    // stage this block's pc2 segment into LDS, SoA
    for (int j = t; j < len; j += TPB) {
        const int g = y0 + j;
        ysx[j] = pc2[3 * g];
        ysy[j] = pc2[3 * g + 1];
        ysz[j] = pc2[3 * g + 2];
    }

    // load + deform this thread's 8 x-points (stride TPB for coalescing)
    const int ibase = blockIdx.x * PTS_PER_BLOCK + t;
    float ax[RB], ay[RB], az[RB];
#pragma unroll
    for (int r = 0; r < RB; ++r) {
        const int i = ibase + r * TPB;
        const int ic = (i < N) ? i : (N - 1);
        ax[r] = pc1[3 * ic]     + flow[3 * ic];
        ay[r] = pc1[3 * ic + 1] + flow[3 * ic + 1];
        az[r] = pc1[3 * ic + 2] + flow[3 * ic + 2];
    }
    __syncthreads();

    float m[RB];
#pragma unroll
    for (int r = 0; r < RB; ++r) m[r] = 3.0e38f;

    if ((len & 3) == 0) {
        const float4* __restrict__ X4 = (const float4*)ysx;
        const float4* __restrict__ Y4 = (const float4*)ysy;
        const float4* __restrict__ Z4 = (const float4*)ysz;
        const int nq = len / 4;
        // software pipeline: prefetch q+1 during q's 176-instr compute
        float4 cYX = X4[0], cYY = Y4[0], cYZ = Z4[0];
        for (int q = 0; q < nq; ++q) {
            float4 nYX, nYY, nYZ;
            if (q + 1 < nq) { nYX = X4[q + 1]; nYY = Y4[q + 1]; nYZ = Z4[q + 1]; }
#pragma unroll
            for (int r = 0; r < RB; ++r) {
                DIST2(m[r], ax[r], ay[r], az[r],
                      cYX.x, cYY.x, cYZ.x, cYX.y, cYY.y, cYZ.y);
                DIST2(m[r], ax[r], ay[r], az[r],
                      cYX.z, cYY.z, cYZ.z, cYX.w, cYY.w, cYZ.w);
            }
            if (q + 1 < nq) { cYX = nYX; cYY = nYY; cYZ = nYZ; }
        }
    } else {
        for (int j = 0; j < len; ++j) {
            const float yx = ysx[j], yy = ysy[j], yz = ysz[j];
#pragma unroll
            for (int r = 0; r < RB; ++r)
                m[r] = fminf(m[r], fabsf(ax[r] - yx) + fabsf(ay[r] - yy) + fabsf(az[r] - yz));
        }
    }

    // exact, order-independent combine: uint order == float order for nonneg
#pragma unroll
    for (int r = 0; r < RB; ++r) {
        const int i = ibase + r * TPB;
        if (i < N) atomicMin(&minbits[i], __float_as_uint(m[r]));
    }
}

// single-block deterministic reduction: out[0] = sum(min) / N
__global__ __launch_bounds__(1024) void reduce_kernel(
    const unsigned* __restrict__ minbits, float* __restrict__ out, int N) {
    float s = 0.0f;
    const uint4* p = (const uint4*)minbits;
    for (int k = threadIdx.x; k < N / 4; k += 1024) {
        uint4 v = p[k];
        s += __uint_as_float(v.x) + __uint_as_float(v.y) +
             __uint_as_float(v.z) + __uint_as_float(v.w);
    }
    for (int k = (N / 4) * 4 + threadIdx.x; k < N; k += 1024)
        s += __uint_as_float(minbits[k]);
#pragma unroll
    for (int off = 32; off > 0; off >>= 1) s += __shfl_down(s, off, 64);
    __shared__ float ls[16];
    const int wid = threadIdx.x >> 6, lane = threadIdx.x & 63;
    if (lane == 0) ls[wid] = s;
    __syncthreads();
    if (threadIdx.x == 0) {
        float tot = 0.0f;
        for (int w = 0; w < 16; ++w) tot += ls[w];
        out[0] = tot / (float)N;
    }
}

extern "C" void kernel_launch(void* const* d_in, const int* in_sizes, int n_in,
                              void* d_out, int out_size, void* d_ws, size_t ws_size,
                              hipStream_t stream) {
    const float* pc1  = (const float*)d_in[0];
    const float* flow = (const float*)d_in[1];
    const float* pc2  = (const float*)d_in[2];
    float* out = (float*)d_out;

    const int N = in_sizes[0] / 3;
    const int M = in_sizes[2] / 3;

    unsigned* minbits = (unsigned*)d_ws;

    // freespace_loss part of d_out stays zero; out[0] overwritten by reduce
    hipMemsetAsync(d_out, 0, (size_t)out_size * sizeof(float), stream);
    // 0x7F7F7F7F = 3.39e38f sentinel; uint order == float order for nonneg
    hipMemsetAsync(minbits, 0x7F, (size_t)N * sizeof(unsigned), stream);

    const int nbN    = (N + PTS_PER_BLOCK - 1) / PTS_PER_BLOCK;  // 8
    const int msplit = (M + MSEG - 1) / MSEG;                    // 128 -> grid 1024

    chamfer_kernel<<<dim3(nbN, msplit), TPB, 0, stream>>>(pc1, flow, pc2, minbits, N, M);
    reduce_kernel<<<1, 1024, 0, stream>>>(minbits, out, N);
}

// Round 6
// 42.117 us; speedup vs baseline: 1.5694x; 1.0557x over previous
//
#include <hip/hip_runtime.h>

// One-way Chamfer (L1, K=1): out[0] = mean_i min_j ||x_i - y_j||_1 ; out[1..N] = 0
// N = M = 16384, D = 3, fp32.
//
// R6: R5's asm cut instruction count but issue efficiency stayed ~55-60%
// (chamfer ~35us vs 19us of issue): DIST2 ended with back-to-back dependent
// adds+min3 and only 4 waves/SIMD were resident to hide the bubbles.
// Fixes: (1) 100% occupancy - RB=4, grid 16x128=2048 blocks, 8 blocks/CU
// via __launch_bounds__(256,8); (2) interleaved DIST2 (two distance chains
// spaced >=2 apart, 5 temps, single min3 bubble); (3) ping-pong tile
// pipeline loading directly into named float4 regs (no v_mov copies).

#define TPB 256
#define RB 4
#define PTS_PER_BLOCK (TPB * RB)   // 1024
#define MSEG 128                   // y-points staged in LDS per block

// d0=|ax-y0|_1, d1=|ax-y1|_1, MR=min3(MR,d0,d1): 11 VALU instrs / 2 pairs,
// chains interleaved so no dep is closer than 2 instrs (except final min3).
#define DIST2(MR, AXv, AYv, AZv, Y0X, Y0Y, Y0Z, Y1X, Y1Y, Y1Z)            \
  {                                                                        \
    float t0, t1, t2, t3, t4;                                              \
    asm("v_sub_f32 %1, %6, %9\n\t"                                         \
        "v_sub_f32 %2, %7, %10\n\t"                                        \
        "v_sub_f32 %3, %8, %11\n\t"                                        \
        "v_sub_f32 %4, %6, %12\n\t"                                        \
        "v_sub_f32 %5, %7, %13\n\t"                                        \
        "v_add_f32 %1, |%1|, |%2|\n\t"                                     \
        "v_sub_f32 %2, %8, %14\n\t"                                        \
        "v_add_f32 %4, |%4|, |%5|\n\t"                                     \
        "v_add_f32 %1, %1, |%3|\n\t"                                       \
        "v_add_f32 %4, %4, |%2|\n\t"                                       \
        "v_min3_f32 %0, %0, %1, %4"                                        \
        : "+v"(MR), "=&v"(t0), "=&v"(t1), "=&v"(t2), "=&v"(t3), "=&v"(t4)  \
        : "v"(AXv), "v"(AYv), "v"(AZv),                                    \
          "v"(Y0X), "v"(Y0Y), "v"(Y0Z), "v"(Y1X), "v"(Y1Y), "v"(Y1Z));    \
  }

#define DIST8(Q4X, Q4Y, Q4Z)                                               \
  {                                                                        \
    _Pragma("unroll")                                                      \
    for (int r = 0; r < RB; ++r) {                                         \
      DIST2(m[r], ax[r], ay[r], az[r],                                     \
            Q4X.x, Q4Y.x, Q4Z.x, Q4X.y, Q4Y.y, Q4Z.y);                     \
      DIST2(m[r], ax[r], ay[r], az[r],                                     \
            Q4X.z, Q4Y.z, Q4Z.z, Q4X.w, Q4Y.w, Q4Z.w);                     \
    }                                                                      \
  }

__global__ __launch_bounds__(TPB, 8) void chamfer_kernel(
    const float* __restrict__ pc1, const float* __restrict__ flow,
    const float* __restrict__ pc2, unsigned* __restrict__ minbits,
    int N, int M) {
    // +4 pad so the pipeline's one-past-the-end prefetch stays in bounds
    __shared__ float ysx[MSEG + 4], ysy[MSEG + 4], ysz[MSEG + 4];

    const int t  = threadIdx.x;
    const int y0 = blockIdx.y * MSEG;
    const int len = (M - y0 < MSEG) ? (M - y0) : MSEG;

    // stage this block's pc2 segment into LDS, SoA
    for (int j = t; j < len; j += TPB) {
        const int g = y0 + j;
        ysx[j] = pc2[3 * g];
        ysy[j] = pc2[3 * g + 1];
        ysz[j] = pc2[3 * g + 2];
    }

    // load + deform this thread's 4 x-points (stride TPB for coalescing)
    const int ibase = blockIdx.x * PTS_PER_BLOCK + t;
    float ax[RB], ay[RB], az[RB];
#pragma unroll
    for (int r = 0; r < RB; ++r) {
        const int i = ibase + r * TPB;
        const int ic = (i < N) ? i : (N - 1);
        ax[r] = pc1[3 * ic]     + flow[3 * ic];
        ay[r] = pc1[3 * ic + 1] + flow[3 * ic + 1];
        az[r] = pc1[3 * ic + 2] + flow[3 * ic + 2];
    }
    __syncthreads();

    float m[RB];
#pragma unroll
    for (int r = 0; r < RB; ++r) m[r] = 3.0e38f;

    if ((len & 7) == 0) {
        const float4* __restrict__ X4 = (const float4*)ysx;
        const float4* __restrict__ Y4 = (const float4*)ysy;
        const float4* __restrict__ Z4 = (const float4*)ysz;
        const int nq = len >> 2;
        // 2-deep ping-pong: loads go straight into named regs, no copies
        float4 aX = X4[0], aY = Y4[0], aZ = Z4[0];
        for (int q = 0; q < nq; q += 2) {
            float4 bX = X4[q + 1], bY = Y4[q + 1], bZ = Z4[q + 1];
            DIST8(aX, aY, aZ);
            aX = X4[q + 2]; aY = Y4[q + 2]; aZ = Z4[q + 2];  // pad-safe at q+2==nq
            DIST8(bX, bY, bZ);
        }
    } else {
        for (int j = 0; j < len; ++j) {
            const float yx = ysx[j], yy = ysy[j], yz = ysz[j];
#pragma unroll
            for (int r = 0; r < RB; ++r)
                m[r] = fminf(m[r], fabsf(ax[r] - yx) + fabsf(ay[r] - yy) + fabsf(az[r] - yz));
        }
    }

    // exact, order-independent combine: uint order == float order for nonneg
#pragma unroll
    for (int r = 0; r < RB; ++r) {
        const int i = ibase + r * TPB;
        if (i < N) atomicMin(&minbits[i], __float_as_uint(m[r]));
    }
}

// single-block deterministic reduction: out[0] = sum(min) / N
__global__ __launch_bounds__(1024) void reduce_kernel(
    const unsigned* __restrict__ minbits, float* __restrict__ out, int N) {
    float s = 0.0f;
    const uint4* p = (const uint4*)minbits;
    for (int k = threadIdx.x; k < N / 4; k += 1024) {
        uint4 v = p[k];
        s += __uint_as_float(v.x) + __uint_as_float(v.y) +
             __uint_as_float(v.z) + __uint_as_float(v.w);
    }
    for (int k = (N / 4) * 4 + threadIdx.x; k < N; k += 1024)
        s += __uint_as_float(minbits[k]);
#pragma unroll
    for (int off = 32; off > 0; off >>= 1) s += __shfl_down(s, off, 64);
    __shared__ float ls[16];
    const int wid = threadIdx.x >> 6, lane = threadIdx.x & 63;
    if (lane == 0) ls[wid] = s;
    __syncthreads();
    if (threadIdx.x == 0) {
        float tot = 0.0f;
        for (int w = 0; w < 16; ++w) tot += ls[w];
        out[0] = tot / (float)N;
    }
}

extern "C" void kernel_launch(void* const* d_in, const int* in_sizes, int n_in,
                              void* d_out, int out_size, void* d_ws, size_t ws_size,
                              hipStream_t stream) {
    const float* pc1  = (const float*)d_in[0];
    const float* flow = (const float*)d_in[1];
    const float* pc2  = (const float*)d_in[2];
    float* out = (float*)d_out;

    const int N = in_sizes[0] / 3;
    const int M = in_sizes[2] / 3;

    unsigned* minbits = (unsigned*)d_ws;

    // freespace_loss part of d_out stays zero; out[0] overwritten by reduce
    hipMemsetAsync(d_out, 0, (size_t)out_size * sizeof(float), stream);
    // 0x7F7F7F7F = 3.39e38f sentinel; uint order == float order for nonneg
    hipMemsetAsync(minbits, 0x7F, (size_t)N * sizeof(unsigned), stream);

    const int nbN    = (N + PTS_PER_BLOCK - 1) / PTS_PER_BLOCK;  // 16
    const int msplit = (M + MSEG - 1) / MSEG;                    // 128 -> grid 2048

    chamfer_kernel<<<dim3(nbN, msplit), TPB, 0, stream>>>(pc1, flow, pc2, minbits, N, M);
    reduce_kernel<<<1, 1024, 0, stream>>>(minbits, out, N);
}